// Round 5
// baseline (376.533 us; speedup 1.0000x reference)
//
#include <hip/hip_runtime.h>

#define D 128
#define AGGB 3136    // gather blocks: 3136*8 halfwaves * 2 rows * 2 iters = 100352
#define MAXDEG 16    // direct CSR slots per receiver
#define OVFCAP 16384 // overflow pair capacity

typedef __attribute__((ext_vector_type(8))) short short8;
typedef __attribute__((ext_vector_type(4))) float floatx4;

// RNE split of fp32 into bf16 hi + bf16 lo (x ~= hi + lo, err ~2^-17 |x|)
__device__ inline void bf16split(float x, ushort& hi, ushort& lo) {
  unsigned u = __float_as_uint(x);
  unsigned rh = (u + 0x7FFFu + ((u >> 16) & 1u)) & 0xFFFF0000u;
  hi = (ushort)(rh >> 16);
  float fl = x - __uint_as_float(rh);
  unsigned ul = __float_as_uint(fl);
  lo = (ushort)((ul + 0x7FFFu + ((ul >> 16) & 1u)) >> 16);
}

__device__ inline void place_edge(int s, int r, int p, int* __restrict__ srtp,
                                  int* __restrict__ ovf, int* __restrict__ ovfn) {
  if (p < MAXDEG) {
    srtp[r * MAXDEG + p] = s;
  } else {
    const int q = atomicAdd(ovfn, 1);
    if (q < OVFCAP) {
      ovf[2 * q] = r;
      ovf[2 * q + 1] = s;
    }
  }
}

// K0 (tiny): block 0: gvec = g@W3 + b3; blocks [1,129): W1/W2 bf16 hi/lo
// transpose-split into wt[mat][plane][n][k]. Runs BEFORE k_eg so gemm1 blocks
// can read wt without racing the split.
__global__ void k_prep(const float* __restrict__ g, const float* __restrict__ W3,
                       const float* __restrict__ b3, float* __restrict__ gvec,
                       const float* __restrict__ W1, const float* __restrict__ W2,
                       ushort* __restrict__ wt) {
  const int b = blockIdx.x;
  if (b == 0) {
    __shared__ float part[256];
    const int j = threadIdx.x & 127, half = threadIdx.x >> 7;
    float acc = 0.f;
    for (int k = half * 64; k < half * 64 + 64; ++k)
      acc = fmaf(g[k], W3[k * D + j], acc);
    part[threadIdx.x] = acc;
    __syncthreads();
    if (threadIdx.x < D) gvec[j] = b3[j] + part[j] + part[j + 128];
    return;
  }
  const int id = (b - 1) * 256 + threadIdx.x;  // 32768 ids
  const int mat = id >> 14, idx = id & 16383;
  const int k = idx >> 7, nn = idx & 127;
  const float x = (mat ? W2 : W1)[k * D + nn];
  ushort hi, lo;
  bf16split(x, hi, lo);
  wt[(size_t)mat * 32768 + (size_t)nn * 128 + k] = hi;
  wt[(size_t)mat * 32768 + 16384 + (size_t)nn * 128 + k] = lo;
}

// K1: co-dispatched independent phases.
// blocks [0,nbE4): edge pass, 4 edges/thread — int4 loads, 8 independent
//   atomics in flight per thread (vs 2 in R4) to raise atomic MLP; recv atomic
//   also places the edge into the direct CSR bucket (overflow -> ovf list).
// blocks [nbE4, nbE4+NG): gemm1 h1 = nodes@W1 (raw fp32 into d_out h region),
//   single-A bf16x3 pipeline (double-buffered LDS, depth-2 prefetch, one
//   barrier per pass). Rides entirely under the edge phase's idle resources.
__global__ __launch_bounds__(256, 6) void k_eg(
    const int* __restrict__ snd, const int* __restrict__ rcv,
    int* __restrict__ cs, int* __restrict__ cr, int* __restrict__ srtp,
    int* __restrict__ ovf, int* __restrict__ ovfn, int E, int nbE4,
    const float* __restrict__ A, const ushort* __restrict__ wt,
    float* __restrict__ h1, int n) {
  const int b = blockIdx.x, t = threadIdx.x;
  if (b < nbE4) {
    const int e0 = b * 1024 + t * 4;
    if (e0 + 3 < E) {
      const int4 s4 = *(const int4*)(snd + e0);
      const int4 r4 = *(const int4*)(rcv + e0);
      atomicAdd(cs + s4.x, 1);
      atomicAdd(cs + s4.y, 1);
      atomicAdd(cs + s4.z, 1);
      atomicAdd(cs + s4.w, 1);
      const int p0 = atomicAdd(cr + r4.x, 1);
      const int p1 = atomicAdd(cr + r4.y, 1);
      const int p2 = atomicAdd(cr + r4.z, 1);
      const int p3 = atomicAdd(cr + r4.w, 1);
      place_edge(s4.x, r4.x, p0, srtp, ovf, ovfn);
      place_edge(s4.y, r4.y, p1, srtp, ovf, ovfn);
      place_edge(s4.z, r4.z, p2, srtp, ovf, ovfn);
      place_edge(s4.w, r4.w, p3, srtp, ovf, ovfn);
    } else {
      for (int e = e0; e < E && e < e0 + 4; ++e) {
        const int s = snd[e], r = rcv[e];
        atomicAdd(cs + s, 1);
        place_edge(s, r, atomicAdd(cr + r, 1), srtp, ovf, ovfn);
      }
    }
    return;
  }
  // ---- gemm1: h1 = nodes @ W1 (64x128 tile, 4 waves, wave w: cols w*32..+31)
  __shared__ ushort As[2 * 2 * 2560];  // [buf][plane hi/lo][64*40], 20 KB
  const int row0 = (b - nbE4) * 64;
  const int lane = t & 63, w = t >> 6;
  const int m = lane & 15, quad = lane >> 4;

  floatx4 acc[4][2];
#pragma unroll
  for (int i = 0; i < 4; ++i)
#pragma unroll
    for (int j = 0; j < 2; ++j) acc[i][j] = (floatx4)0.f;

  const int srow = t >> 2, ko = (t & 3) * 8;
  const int grow = min(row0 + srow, n - 1);
  const float* Ag = A + (size_t)grow * D + ko;
  const int sa = srow * 40 + ko;

  float4 f0, f1;
#define LOADP(p)                              \
  {                                           \
    f0 = *(const float4*)(Ag + (p) * 32);     \
    f1 = *(const float4*)(Ag + (p) * 32 + 4); \
  }
#define STOREB(buf)                                               \
  {                                                               \
    ushort h0, l0, h1_, l1_, h2, l2, h3, l3;                      \
    ushort* Bp = &As[(buf) * 5120];                               \
    bf16split(f0.x, h0, l0); bf16split(f0.y, h1_, l1_);           \
    bf16split(f0.z, h2, l2); bf16split(f0.w, h3, l3);             \
    *(ushort4*)&Bp[sa] = make_ushort4(h0, h1_, h2, h3);           \
    *(ushort4*)&Bp[2560 + sa] = make_ushort4(l0, l1_, l2, l3);    \
    bf16split(f1.x, h0, l0); bf16split(f1.y, h1_, l1_);           \
    bf16split(f1.z, h2, l2); bf16split(f1.w, h3, l3);             \
    *(ushort4*)&Bp[sa + 4] = make_ushort4(h0, h1_, h2, h3);       \
    *(ushort4*)&Bp[2560 + sa + 4] = make_ushort4(l0, l1_, l2, l3);\
  }

  LOADP(0);
  STOREB(0);
  LOADP(1);
  __syncthreads();

  for (int p = 0; p < 4; ++p) {
    if (p < 3) STOREB((p + 1) & 1);
    if (p < 2) LOADP(p + 2);
    const ushort* Ab = &As[(p & 1) * 5120];
#pragma unroll
    for (int j = 0; j < 2; ++j) {
      const ushort* g1 = wt + (size_t)(w * 32 + j * 16 + m) * 128 + p * 32 + quad * 8;
      const short8 w1h = *(const short8*)g1;
      const short8 w1l = *(const short8*)(g1 + 16384);
#pragma unroll
      for (int i = 0; i < 4; ++i) {
        const int r = (i * 16 + m) * 40 + quad * 8;
        const short8 a1h = *(const short8*)&Ab[r];
        const short8 a1l = *(const short8*)&Ab[2560 + r];
        floatx4 c = acc[i][j];
        c = __builtin_amdgcn_mfma_f32_16x16x32_bf16(a1h, w1h, c, 0, 0, 0);
        c = __builtin_amdgcn_mfma_f32_16x16x32_bf16(a1h, w1l, c, 0, 0, 0);
        c = __builtin_amdgcn_mfma_f32_16x16x32_bf16(a1l, w1h, c, 0, 0, 0);
        acc[i][j] = c;
      }
    }
    __syncthreads();
  }
#undef LOADP
#undef STOREB

  // raw h1 out (bias/relu/residual applied later in k_gemm2)
#pragma unroll
  for (int i = 0; i < 4; ++i)
#pragma unroll
    for (int pp = 0; pp < 4; ++pp) {
      const int rg = row0 + i * 16 + quad * 4 + pp;
      if (rg >= n) continue;
#pragma unroll
      for (int j = 0; j < 2; ++j)
        h1[(size_t)rg * D + w * 32 + j * 16 + m] = acc[i][j][pp];
    }
}

// K2: aggregate-first gather via direct CSR. y_r = rs_r * sum_s rs_s*nodes_s
// (bf16 hi/lo planes), c_r = rs_r * sum_s rs_s (overwrites cnt_recv as float).
// Half-wave per row, float4/lane, two rows in flight; slot indices via int4.
__global__ __launch_bounds__(256) void k_agg(
    const float* __restrict__ nodes, int* __restrict__ cnt_recv,
    const int* __restrict__ cnt_send, const int* __restrict__ srtp,
    const int* __restrict__ ovf, const int* __restrict__ ovfn,
    ushort* __restrict__ yh, ushort* __restrict__ yl, int n) {
  float* cf = (float*)cnt_recv;
  const int hw = threadIdx.x >> 5, ln = threadIdx.x & 31;
  const int ghw = blockIdx.x * 8 + hw;
  const int nhw = AGGB * 8;
  const int c0 = ln * 4;

  for (int r0 = ghw; r0 < n; r0 += 2 * nhw) {
    const int r1 = r0 + nhw;
    const bool has1 = r1 < n;
    const int dg0 = cnt_recv[r0];
    const int dg1 = has1 ? cnt_recv[r1] : 0;
    const int base0 = r0 * MAXDEG;
    const int base1 = (has1 ? r1 : 0) * MAXDEG;

    const int4 qa0 = *(const int4*)(srtp + base0);
    const int4 qb0 = *(const int4*)(srtp + base0 + 4);
    const int4 qa1 = *(const int4*)(srtp + base1);
    const int4 qb1 = *(const int4*)(srtp + base1 + 4);
    int idx0[8] = {qa0.x, qa0.y, qa0.z, qa0.w, qb0.x, qb0.y, qb0.z, qb0.w};
    int idx1[8] = {qa1.x, qa1.y, qa1.z, qa1.w, qb1.x, qb1.y, qb1.z, qb1.w};
#pragma unroll
    for (int j = 0; j < 8; ++j) {  // unwritten slots hold garbage -> select 0
      idx0[j] = (j < dg0) ? idx0[j] : 0;
      idx1[j] = (j < dg1) ? idx1[j] : 0;
    }
    float4 g0[8], g1[8];
#pragma unroll
    for (int j = 0; j < 8; ++j)
      g0[j] = *(const float4*)(nodes + (size_t)idx0[j] * D + c0);
#pragma unroll
    for (int j = 0; j < 8; ++j)
      g1[j] = *(const float4*)(nodes + (size_t)idx1[j] * D + c0);
    float rs0[8], rs1[8];
#pragma unroll
    for (int j = 0; j < 8; ++j) {
      rs0[j] = (j < dg0) ? rsqrtf(fmaxf((float)cnt_send[idx0[j]], 1.f)) : 0.f;
      rs1[j] = (j < dg1) ? rsqrtf(fmaxf((float)cnt_send[idx1[j]], 1.f)) : 0.f;
    }

    float sx0 = 0.f, sy0 = 0.f, sz0 = 0.f, sw0 = 0.f, cs0 = 0.f;
    float sx1 = 0.f, sy1 = 0.f, sz1 = 0.f, sw1 = 0.f, cs1 = 0.f;
#pragma unroll
    for (int j = 0; j < 8; ++j) {
      sx0 = fmaf(rs0[j], g0[j].x, sx0);
      sy0 = fmaf(rs0[j], g0[j].y, sy0);
      sz0 = fmaf(rs0[j], g0[j].z, sz0);
      sw0 = fmaf(rs0[j], g0[j].w, sw0);
      cs0 += rs0[j];
      sx1 = fmaf(rs1[j], g1[j].x, sx1);
      sy1 = fmaf(rs1[j], g1[j].y, sy1);
      sz1 = fmaf(rs1[j], g1[j].z, sz1);
      sw1 = fmaf(rs1[j], g1[j].w, sw1);
      cs1 += rs1[j];
    }
    for (int i = 8; i < min(dg0, MAXDEG); ++i) {
      const int s = srtp[base0 + i];
      const float r = rsqrtf(fmaxf((float)cnt_send[s], 1.f));
      const float4 c = *(const float4*)(nodes + (size_t)s * D + c0);
      sx0 = fmaf(r, c.x, sx0); sy0 = fmaf(r, c.y, sy0);
      sz0 = fmaf(r, c.z, sz0); sw0 = fmaf(r, c.w, sw0);
      cs0 += r;
    }
    for (int i = 8; i < min(dg1, MAXDEG); ++i) {
      const int s = srtp[base1 + i];
      const float r = rsqrtf(fmaxf((float)cnt_send[s], 1.f));
      const float4 c = *(const float4*)(nodes + (size_t)s * D + c0);
      sx1 = fmaf(r, c.x, sx1); sy1 = fmaf(r, c.y, sy1);
      sz1 = fmaf(r, c.z, sz1); sw1 = fmaf(r, c.w, sw1);
      cs1 += r;
    }
    if (dg0 > MAXDEG) {  // rare overflow rows
      const int novf = min(*ovfn, OVFCAP);
      for (int k2 = 0; k2 < novf; ++k2) {
        if (ovf[2 * k2] == r0) {
          const int s = ovf[2 * k2 + 1];
          const float r = rsqrtf(fmaxf((float)cnt_send[s], 1.f));
          const float4 c = *(const float4*)(nodes + (size_t)s * D + c0);
          sx0 = fmaf(r, c.x, sx0); sy0 = fmaf(r, c.y, sy0);
          sz0 = fmaf(r, c.z, sz0); sw0 = fmaf(r, c.w, sw0);
          cs0 += r;
        }
      }
    }
    if (dg1 > MAXDEG) {
      const int novf = min(*ovfn, OVFCAP);
      for (int k2 = 0; k2 < novf; ++k2) {
        if (ovf[2 * k2] == r1) {
          const int s = ovf[2 * k2 + 1];
          const float r = rsqrtf(fmaxf((float)cnt_send[s], 1.f));
          const float4 c = *(const float4*)(nodes + (size_t)s * D + c0);
          sx1 = fmaf(r, c.x, sx1); sy1 = fmaf(r, c.y, sy1);
          sz1 = fmaf(r, c.z, sz1); sw1 = fmaf(r, c.w, sw1);
          cs1 += r;
        }
      }
    }

    {
      const float rr = rsqrtf(fmaxf((float)dg0, 1.f));
      ushort h0, l0, h1, l1, h2, l2, h3, l3;
      bf16split(sx0 * rr, h0, l0);
      bf16split(sy0 * rr, h1, l1);
      bf16split(sz0 * rr, h2, l2);
      bf16split(sw0 * rr, h3, l3);
      *(ushort4*)(yh + (size_t)r0 * D + c0) = make_ushort4(h0, h1, h2, h3);
      *(ushort4*)(yl + (size_t)r0 * D + c0) = make_ushort4(l0, l1, l2, l3);
      if (ln == 0) cf[r0] = rr * cs0;
    }
    if (has1) {
      const float rr = rsqrtf(fmaxf((float)dg1, 1.f));
      ushort h0, l0, h1, l1, h2, l2, h3, l3;
      bf16split(sx1 * rr, h0, l0);
      bf16split(sy1 * rr, h1, l1);
      bf16split(sz1 * rr, h2, l2);
      bf16split(sw1 * rr, h3, l3);
      *(ushort4*)(yh + (size_t)r1 * D + c0) = make_ushort4(h0, h1, h2, h3);
      *(ushort4*)(yl + (size_t)r1 * D + c0) = make_ushort4(l0, l1, l2, l3);
      if (ln == 0) cf[r1] = rr * cs1;
    }
  }
}

// K3: y@W2 GEMM + full epilogue. A2 = pre-split y planes (pure uint4 staging),
// double-buffered LDS, depth-2 prefetch, one barrier per pass. Reads h1 from
// hio (d_out) at the exact addresses it overwrites with h (same thread ->
// ordered; each element owned by one thread).
// h = relu(h1 + y@W2 + b1 + c*b2 + gvec) + nodes; an += column sums.
__global__ __launch_bounds__(256, 6) void k_gemm2(
    const float* __restrict__ A, const ushort* __restrict__ yh,
    const ushort* __restrict__ yl, const ushort* __restrict__ wt,
    const float* __restrict__ b1, const float* __restrict__ b2,
    const float* __restrict__ gvec, const float* __restrict__ cf,
    float* hio, float* __restrict__ an, int n) {
  __shared__ ushort As[2 * 2 * 2560];  // [buf][plane y_hi/y_lo][64*40], 20 KB
  const int t = threadIdx.x;
  const int row0 = blockIdx.x * 64;
  const int lane = t & 63, w = t >> 6;
  const int m = lane & 15, quad = lane >> 4;

  floatx4 acc[4][2];
#pragma unroll
  for (int i = 0; i < 4; ++i)
#pragma unroll
    for (int j = 0; j < 2; ++j) acc[i][j] = (floatx4)0.f;

  const int srow = t >> 2, ko = (t & 3) * 8;
  const int grow = min(row0 + srow, n - 1);
  const ushort* yhb = yh + (size_t)grow * D + ko;
  const ushort* ylb = yl + (size_t)grow * D + ko;
  const int sa = srow * 40 + ko;

  uint4 r2, r3;
#define LOADP(p)                          \
  {                                       \
    r2 = *(const uint4*)(yhb + (p) * 32); \
    r3 = *(const uint4*)(ylb + (p) * 32); \
  }
#define STOREB(buf)                 \
  {                                 \
    ushort* Bp = &As[(buf) * 5120]; \
    *(uint4*)&Bp[sa] = r2;          \
    *(uint4*)&Bp[2560 + sa] = r3;   \
  }

  LOADP(0);
  STOREB(0);
  LOADP(1);
  __syncthreads();

  for (int p = 0; p < 4; ++p) {
    if (p < 3) STOREB((p + 1) & 1);
    if (p < 2) LOADP(p + 2);
    const ushort* Ab = &As[(p & 1) * 5120];
#pragma unroll
    for (int j = 0; j < 2; ++j) {
      const ushort* g2 =
          wt + 32768 + (size_t)(w * 32 + j * 16 + m) * 128 + p * 32 + quad * 8;
      const short8 w2h = *(const short8*)g2;
      const short8 w2l = *(const short8*)(g2 + 16384);
#pragma unroll
      for (int i = 0; i < 4; ++i) {
        const int r = (i * 16 + m) * 40 + quad * 8;
        const short8 a2h = *(const short8*)&Ab[r];
        const short8 a2l = *(const short8*)&Ab[2560 + r];
        floatx4 c = acc[i][j];
        c = __builtin_amdgcn_mfma_f32_16x16x32_bf16(a2h, w2h, c, 0, 0, 0);
        c = __builtin_amdgcn_mfma_f32_16x16x32_bf16(a2h, w2l, c, 0, 0, 0);
        c = __builtin_amdgcn_mfma_f32_16x16x32_bf16(a2l, w2h, c, 0, 0, 0);
        acc[i][j] = c;
      }
    }
    __syncthreads();
  }
#undef LOADP
#undef STOREB

  float bb[2], b2c[2];
#pragma unroll
  for (int j = 0; j < 2; ++j) {
    const int col = w * 32 + j * 16 + m;
    bb[j] = b1[col] + gvec[col];
    b2c[j] = b2[col];
  }
  float asum[2] = {0.f, 0.f};
#pragma unroll
  for (int i = 0; i < 4; ++i)
#pragma unroll
    for (int pp = 0; pp < 4; ++pp) {
      const int rg = row0 + i * 16 + quad * 4 + pp;
      if (rg >= n) continue;
      const float crv = cf[rg];
#pragma unroll
      for (int j = 0; j < 2; ++j) {
        const int col = w * 32 + j * 16 + m;
        float v = acc[i][j][pp] + bb[j] + crv * b2c[j] + hio[(size_t)rg * D + col];
        v = fmaxf(v, 0.f) + A[(size_t)rg * D + col];
        hio[(size_t)rg * D + col] = v;
        asum[j] += v;
      }
    }
#pragma unroll
  for (int j = 0; j < 2; ++j) {
    float v = asum[j];
    v += __shfl_xor(v, 16);
    v += __shfl_xor(v, 32);
    if (lane < 16) atomicAdd(an + w * 32 + j * 16 + m, v);
  }
}

// K4: g_new = globals + relu(concat([an, globals]) @ Wg + bg), 2-way k-split
__global__ void k_gupdate(const float* __restrict__ an, const float* __restrict__ g,
                          const float* __restrict__ Wg, const float* __restrict__ bg,
                          float* __restrict__ gout) {
  __shared__ float part[256];
  const int j = threadIdx.x & 127, half = threadIdx.x >> 7;
  float acc = 0.f;
  if (half == 0) {
    for (int k = 0; k < D; ++k) acc = fmaf(an[k], Wg[k * D + j], acc);
  } else {
    for (int k = 0; k < D; ++k) acc = fmaf(g[k], Wg[(D + k) * D + j], acc);
  }
  part[threadIdx.x] = acc;
  __syncthreads();
  if (threadIdx.x < D)
    gout[j] = g[j] + fmaxf(bg[j] + part[j] + part[j + 128], 0.f);
}

extern "C" void kernel_launch(void* const* d_in, const int* in_sizes, int n_in,
                              void* d_out, int out_size, void* d_ws, size_t ws_size,
                              hipStream_t stream) {
  const float* nodes = (const float*)d_in[0];
  const float* globals_ = (const float*)d_in[1];
  const int* senders = (const int*)d_in[2];
  const int* receivers = (const int*)d_in[3];
  const float* W1_w = (const float*)d_in[4];
  const float* W1_b = (const float*)d_in[5];
  const float* W2_w = (const float*)d_in[6];
  const float* W2_b = (const float*)d_in[7];
  const float* W3_w = (const float*)d_in[8];
  const float* W3_b = (const float*)d_in[9];
  const float* Wg_w = (const float*)d_in[10];
  const float* Wg_b = (const float*)d_in[11];
  const int N = in_sizes[0] / D;
  const int E = in_sizes[2];
  const int nbE4 = (E + 1023) / 1024;  // 4 edges/thread
  const int NG = (N + 63) / 64;

  float* h = (float*)d_out;
  float* gout = h + (size_t)N * D;

  float* ws = (float*)d_ws;
  ushort* yh = (ushort*)ws;                    // N*128 ushorts
  ushort* yl = yh + (size_t)N * D;             // N*128 ushorts
  int* cnt_send = (int*)(yl + (size_t)N * D);  // N   (zeroed)
  int* cnt_recv = cnt_send + N;                // N   (zeroed; becomes c_r float)
  float* an = (float*)(cnt_recv + N);          // D   (zeroed)
  int* ovfn = (int*)(an + D);                  // 1 (+63 pad, zeroed)
  float* gvec = (float*)(ovfn + 64);           // D
  int* srtp = (int*)(gvec + D);                // N*MAXDEG direct CSR
  int* ovf = srtp + (size_t)N * MAXDEG;        // 2*OVFCAP
  ushort* wt = (ushort*)(ovf + 2 * OVFCAP);    // 128 KB split weights

  (void)hipMemsetAsync(cnt_send, 0, (size_t)(2 * N + D + 64) * sizeof(int), stream);

  hipLaunchKernelGGL(k_prep, dim3(129), dim3(256), 0, stream,
                     globals_, W3_w, W3_b, gvec, W1_w, W2_w, wt);
  hipLaunchKernelGGL(k_eg, dim3(nbE4 + NG), dim3(256), 0, stream,
                     senders, receivers, cnt_send, cnt_recv, srtp, ovf, ovfn,
                     E, nbE4, nodes, wt, h, N);
  hipLaunchKernelGGL(k_agg, dim3(AGGB), dim3(256), 0, stream,
                     nodes, cnt_recv, cnt_send, srtp, ovf, ovfn, yh, yl, N);
  hipLaunchKernelGGL(k_gemm2, dim3(NG), dim3(256), 0, stream,
                     nodes, yh, yl, wt, W1_b, W2_b, gvec,
                     (const float*)cnt_recv, h, an, N);
  hipLaunchKernelGGL(k_gupdate, dim3(1), dim3(256), 0, stream, an, globals_,
                     Wg_w, Wg_b, gout);
}

// Round 8
// 342.345 us; speedup vs baseline: 1.0999x; 1.0999x over previous
//
#include <hip/hip_runtime.h>

#define D 128
#define MAXDEG 16     // direct CSR slots per receiver (P(deg>16|Poi(6.4)) ~ 3e-4)
#define OVFCAP 16384  // overflow pair capacity

typedef __attribute__((ext_vector_type(8))) short short8;
typedef __attribute__((ext_vector_type(4))) float floatx4;

// RNE split of fp32 into bf16 hi + bf16 lo (x ~= hi + lo, err ~2^-17 |x|)
__device__ inline void bf16split(float x, ushort& hi, ushort& lo) {
  unsigned u = __float_as_uint(x);
  unsigned rh = (u + 0x7FFFu + ((u >> 16) & 1u)) & 0xFFFF0000u;
  hi = (ushort)(rh >> 16);
  float fl = x - __uint_as_float(rh);
  unsigned ul = __float_as_uint(fl);
  lo = (ushort)((ul + 0x7FFFu + ((ul >> 16) & 1u)) >> 16);
}

__device__ inline void place_edge(int s, int r, int p, int* __restrict__ srtp,
                                  int* __restrict__ ovf, int* __restrict__ ovfn) {
  if (p < MAXDEG) {
    srtp[r * MAXDEG + p] = s;
  } else {
    const int q = atomicAdd(ovfn, 1);
    if (q < OVFCAP) {
      ovf[2 * q] = r;
      ovf[2 * q + 1] = s;
    }
  }
}

// K0: fused front. blocks [0,nbE4): edge pass, 4 edges/thread (int4 loads, 8
// independent atomics in flight); recv atomic also places edge into direct CSR.
// block nbE4: gvec = g@W3 + b3. blocks (nbE4, nbE4+128]: W1/W2 bf16 split.
__global__ void k_front(const int* __restrict__ snd, const int* __restrict__ rcv,
                        int* __restrict__ cs, int* __restrict__ cr,
                        int* __restrict__ srtp, int* __restrict__ ovf,
                        int* __restrict__ ovfn, int E, int nbE4,
                        const float* __restrict__ g, const float* __restrict__ W3,
                        const float* __restrict__ b3, float* __restrict__ gvec,
                        const float* __restrict__ W1, const float* __restrict__ W2,
                        ushort* __restrict__ wt) {
  const int b = blockIdx.x, t = threadIdx.x;
  if (b < nbE4) {
    const int e0 = b * 1024 + t * 4;
    if (e0 + 3 < E) {
      const int4 s4 = *(const int4*)(snd + e0);
      const int4 r4 = *(const int4*)(rcv + e0);
      atomicAdd(cs + s4.x, 1);
      atomicAdd(cs + s4.y, 1);
      atomicAdd(cs + s4.z, 1);
      atomicAdd(cs + s4.w, 1);
      const int p0 = atomicAdd(cr + r4.x, 1);
      const int p1 = atomicAdd(cr + r4.y, 1);
      const int p2 = atomicAdd(cr + r4.z, 1);
      const int p3 = atomicAdd(cr + r4.w, 1);
      place_edge(s4.x, r4.x, p0, srtp, ovf, ovfn);
      place_edge(s4.y, r4.y, p1, srtp, ovf, ovfn);
      place_edge(s4.z, r4.z, p2, srtp, ovf, ovfn);
      place_edge(s4.w, r4.w, p3, srtp, ovf, ovfn);
    } else {
      for (int e = e0; e < E && e < e0 + 4; ++e) {
        const int s = snd[e], r = rcv[e];
        atomicAdd(cs + s, 1);
        place_edge(s, r, atomicAdd(cr + r, 1), srtp, ovf, ovfn);
      }
    }
    return;
  }
  if (b == nbE4) {
    __shared__ float part[256];
    const int j = t & 127, half = t >> 7;
    float acc = 0.f;
    for (int k = half * 64; k < half * 64 + 64; ++k)
      acc = fmaf(g[k], W3[k * D + j], acc);
    part[t] = acc;
    __syncthreads();
    if (t < D) gvec[j] = b3[j] + part[j] + part[j + 128];
    return;
  }
  const int id = (b - nbE4 - 1) * 256 + t;  // 32768 ids
  const int mat = id >> 14, idx = id & 16383;
  const int k = idx >> 7, nn = idx & 127;
  const float x = (mat ? W2 : W1)[k * D + nn];
  ushort hi, lo;
  bf16split(x, hi, lo);
  wt[(size_t)mat * 32768 + (size_t)nn * 128 + k] = hi;
  wt[(size_t)mat * 32768 + 16384 + (size_t)nn * 128 + k] = lo;
}

// K1: merged gather + dual-A GEMM + epilogue. One block = 32 rows.
// Phase A: half-wave per row (2 rows in flight, paired), gather raw nodes via
//   direct CSR, compute y_r (bf16 hi/lo) + node row planes + cf_r -> LDS.
// Phase B: dual GEMM h = relu(nodes@W1 + y@W2 + b1 + cf*b2 + gvec) + nodes,
//   A frags from LDS (full K staged), W frags direct global->reg (wt L2-hot).
// an accumulated via cross-quad shuffle + fp32 atomics (R4-proven).
// LDS planes: [plane:nh,nl,yh,yl][slice p:0..3][row:0..31 * 40 + kk], 40 KB.
__global__ __launch_bounds__(256, 3) void k_ag2(
    const float* __restrict__ nodes, const int* __restrict__ cr,
    const int* __restrict__ cs, const int* __restrict__ srtp,
    const int* __restrict__ ovf, const int* __restrict__ ovfn,
    const ushort* __restrict__ wt, const float* __restrict__ b1,
    const float* __restrict__ b2, const float* __restrict__ gvec,
    float* __restrict__ h, float* __restrict__ an, int n) {
  __shared__ ushort As[4 * 5120];  // 4 planes x (4 slices x 32row x 40)
  __shared__ float cfl[32];
  const int t = threadIdx.x;
  const int row0 = blockIdx.x * 32;

  // ---------------- Phase A: gather + stage ----------------
  {
    const int hw = t >> 5, ln = t & 31;
    const int c0 = ln * 4;
    const int sl = ln >> 3;          // k-slice 0..3
    const int kk = (ln & 7) * 4;     // offset within slice
    const int sb = sl * 1280 + kk;   // slice base + k offset (row added later)

    for (int it = 0; it < 2; ++it) {
      const int lrA = hw + it * 8;   // rows hw, hw+8
      const int lrB = lrA + 16;      // rows hw+16, hw+24
      const int rA = row0 + lrA, rB = row0 + lrB;
      const bool hasA = rA < n, hasB = rB < n;
      const int dgA = hasA ? cr[rA] : 0;
      const int dgB = hasB ? cr[rB] : 0;
      const int baseA = (hasA ? rA : 0) * MAXDEG;
      const int baseB = (hasB ? rB : 0) * MAXDEG;

      const int4 qa0 = *(const int4*)(srtp + baseA);
      const int4 qb0 = *(const int4*)(srtp + baseA + 4);
      const int4 qa1 = *(const int4*)(srtp + baseB);
      const int4 qb1 = *(const int4*)(srtp + baseB + 4);
      int idxA[8] = {qa0.x, qa0.y, qa0.z, qa0.w, qb0.x, qb0.y, qb0.z, qb0.w};
      int idxB[8] = {qa1.x, qa1.y, qa1.z, qa1.w, qb1.x, qb1.y, qb1.z, qb1.w};
#pragma unroll
      for (int j = 0; j < 8; ++j) {  // unwritten slots hold garbage -> 0
        idxA[j] = (j < dgA) ? idxA[j] : 0;
        idxB[j] = (j < dgB) ? idxB[j] : 0;
      }
      float4 gA[8], gB[8];
#pragma unroll
      for (int j = 0; j < 8; ++j)
        gA[j] = *(const float4*)(nodes + (size_t)idxA[j] * D + c0);
#pragma unroll
      for (int j = 0; j < 8; ++j)
        gB[j] = *(const float4*)(nodes + (size_t)idxB[j] * D + c0);
      // own node rows (residual/A1 staging)
      const float4 ndA = hasA ? *(const float4*)(nodes + (size_t)rA * D + c0)
                              : make_float4(0.f, 0.f, 0.f, 0.f);
      const float4 ndB = hasB ? *(const float4*)(nodes + (size_t)rB * D + c0)
                              : make_float4(0.f, 0.f, 0.f, 0.f);
      float rsA[8], rsB[8];
#pragma unroll
      for (int j = 0; j < 8; ++j) {
        rsA[j] = (j < dgA) ? rsqrtf(fmaxf((float)cs[idxA[j]], 1.f)) : 0.f;
        rsB[j] = (j < dgB) ? rsqrtf(fmaxf((float)cs[idxB[j]], 1.f)) : 0.f;
      }
      float sxA = 0.f, syA = 0.f, szA = 0.f, swA = 0.f, csA = 0.f;
      float sxB = 0.f, syB = 0.f, szB = 0.f, swB = 0.f, csB = 0.f;
#pragma unroll
      for (int j = 0; j < 8; ++j) {
        sxA = fmaf(rsA[j], gA[j].x, sxA);
        syA = fmaf(rsA[j], gA[j].y, syA);
        szA = fmaf(rsA[j], gA[j].z, szA);
        swA = fmaf(rsA[j], gA[j].w, swA);
        csA += rsA[j];
        sxB = fmaf(rsB[j], gB[j].x, sxB);
        syB = fmaf(rsB[j], gB[j].y, syB);
        szB = fmaf(rsB[j], gB[j].z, szB);
        swB = fmaf(rsB[j], gB[j].w, swB);
        csB += rsB[j];
      }
      for (int i = 8; i < min(dgA, MAXDEG); ++i) {
        const int s = srtp[baseA + i];
        const float r = rsqrtf(fmaxf((float)cs[s], 1.f));
        const float4 c = *(const float4*)(nodes + (size_t)s * D + c0);
        sxA = fmaf(r, c.x, sxA); syA = fmaf(r, c.y, syA);
        szA = fmaf(r, c.z, szA); swA = fmaf(r, c.w, swA);
        csA += r;
      }
      for (int i = 8; i < min(dgB, MAXDEG); ++i) {
        const int s = srtp[baseB + i];
        const float r = rsqrtf(fmaxf((float)cs[s], 1.f));
        const float4 c = *(const float4*)(nodes + (size_t)s * D + c0);
        sxB = fmaf(r, c.x, sxB); syB = fmaf(r, c.y, syB);
        szB = fmaf(r, c.z, szB); swB = fmaf(r, c.w, swB);
        csB += r;
      }
      if (dgA > MAXDEG) {  // rare overflow rows
        const int novf = min(*ovfn, OVFCAP);
        for (int k2 = 0; k2 < novf; ++k2)
          if (ovf[2 * k2] == rA) {
            const int s = ovf[2 * k2 + 1];
            const float r = rsqrtf(fmaxf((float)cs[s], 1.f));
            const float4 c = *(const float4*)(nodes + (size_t)s * D + c0);
            sxA = fmaf(r, c.x, sxA); syA = fmaf(r, c.y, syA);
            szA = fmaf(r, c.z, szA); swA = fmaf(r, c.w, swA);
            csA += r;
          }
      }
      if (dgB > MAXDEG) {
        const int novf = min(*ovfn, OVFCAP);
        for (int k2 = 0; k2 < novf; ++k2)
          if (ovf[2 * k2] == rB) {
            const int s = ovf[2 * k2 + 1];
            const float r = rsqrtf(fmaxf((float)cs[s], 1.f));
            const float4 c = *(const float4*)(nodes + (size_t)s * D + c0);
            sxB = fmaf(r, c.x, sxB); syB = fmaf(r, c.y, syB);
            szB = fmaf(r, c.z, szB); swB = fmaf(r, c.w, swB);
            csB += r;
          }
      }
      if (hasA) {
        const float rr = rsqrtf(fmaxf((float)dgA, 1.f));
        ushort h0, l0, h1, l1, h2, l2, h3, l3;
        const int a = sb + lrA * 40;
        bf16split(ndA.x, h0, l0); bf16split(ndA.y, h1, l1);
        bf16split(ndA.z, h2, l2); bf16split(ndA.w, h3, l3);
        *(ushort4*)&As[a] = make_ushort4(h0, h1, h2, h3);
        *(ushort4*)&As[5120 + a] = make_ushort4(l0, l1, l2, l3);
        bf16split(sxA * rr, h0, l0); bf16split(syA * rr, h1, l1);
        bf16split(szA * rr, h2, l2); bf16split(swA * rr, h3, l3);
        *(ushort4*)&As[10240 + a] = make_ushort4(h0, h1, h2, h3);
        *(ushort4*)&As[15360 + a] = make_ushort4(l0, l1, l2, l3);
        if (ln == 0) cfl[lrA] = rr * csA;
      }
      if (hasB) {
        const float rr = rsqrtf(fmaxf((float)dgB, 1.f));
        ushort h0, l0, h1, l1, h2, l2, h3, l3;
        const int a = sb + lrB * 40;
        bf16split(ndB.x, h0, l0); bf16split(ndB.y, h1, l1);
        bf16split(ndB.z, h2, l2); bf16split(ndB.w, h3, l3);
        *(ushort4*)&As[a] = make_ushort4(h0, h1, h2, h3);
        *(ushort4*)&As[5120 + a] = make_ushort4(l0, l1, l2, l3);
        bf16split(sxB * rr, h0, l0); bf16split(syB * rr, h1, l1);
        bf16split(szB * rr, h2, l2); bf16split(swB * rr, h3, l3);
        *(ushort4*)&As[10240 + a] = make_ushort4(h0, h1, h2, h3);
        *(ushort4*)&As[15360 + a] = make_ushort4(l0, l1, l2, l3);
        if (ln == 0) cfl[lrB] = rr * csB;
      }
    }
  }
  __syncthreads();

  // ---------------- Phase B: dual GEMM + epilogue ----------------
  const int lane = t & 63, w = t >> 6;
  const int m = lane & 15, quad = lane >> 4;

  floatx4 acc[2][2];
#pragma unroll
  for (int i = 0; i < 2; ++i)
#pragma unroll
    for (int j = 0; j < 2; ++j) acc[i][j] = (floatx4)0.f;

#pragma unroll
  for (int p = 0; p < 4; ++p) {
#pragma unroll
    for (int j = 0; j < 2; ++j) {
      const ushort* g1 =
          wt + (size_t)(w * 32 + j * 16 + m) * 128 + p * 32 + quad * 8;
      const short8 w1h = *(const short8*)g1;
      const short8 w1l = *(const short8*)(g1 + 16384);
      const short8 w2h = *(const short8*)(g1 + 32768);
      const short8 w2l = *(const short8*)(g1 + 49152);
#pragma unroll
      for (int i = 0; i < 2; ++i) {
        const int off = p * 1280 + (i * 16 + m) * 40 + quad * 8;
        const short8 a1h = *(const short8*)&As[off];
        const short8 a1l = *(const short8*)&As[5120 + off];
        const short8 a2h = *(const short8*)&As[10240 + off];
        const short8 a2l = *(const short8*)&As[15360 + off];
        floatx4 c = acc[i][j];
        c = __builtin_amdgcn_mfma_f32_16x16x32_bf16(a1h, w1h, c, 0, 0, 0);
        c = __builtin_amdgcn_mfma_f32_16x16x32_bf16(a1h, w1l, c, 0, 0, 0);
        c = __builtin_amdgcn_mfma_f32_16x16x32_bf16(a1l, w1h, c, 0, 0, 0);
        c = __builtin_amdgcn_mfma_f32_16x16x32_bf16(a2h, w2h, c, 0, 0, 0);
        c = __builtin_amdgcn_mfma_f32_16x16x32_bf16(a2h, w2l, c, 0, 0, 0);
        c = __builtin_amdgcn_mfma_f32_16x16x32_bf16(a2l, w2h, c, 0, 0, 0);
        acc[i][j] = c;
      }
    }
  }

  float bb[2], b2c[2];
#pragma unroll
  for (int j = 0; j < 2; ++j) {
    const int col = w * 32 + j * 16 + m;
    bb[j] = b1[col] + gvec[col];
    b2c[j] = b2[col];
  }
  float asum[2] = {0.f, 0.f};
#pragma unroll
  for (int i = 0; i < 2; ++i)
#pragma unroll
    for (int pp = 0; pp < 4; ++pp) {
      const int lr = i * 16 + quad * 4 + pp;
      const int rg = row0 + lr;
      if (rg >= n) continue;
      const float crv = cfl[lr];
#pragma unroll
      for (int j = 0; j < 2; ++j) {
        const int col = w * 32 + j * 16 + m;
        float v = acc[i][j][pp] + bb[j] + crv * b2c[j];
        v = fmaxf(v, 0.f) + nodes[(size_t)rg * D + col];
        h[(size_t)rg * D + col] = v;
        asum[j] += v;
      }
    }
#pragma unroll
  for (int j = 0; j < 2; ++j) {
    float v = asum[j];
    v += __shfl_xor(v, 16);
    v += __shfl_xor(v, 32);
    if (lane < 16) atomicAdd(an + w * 32 + j * 16 + m, v);
  }
}

// K2: g_new = globals + relu(concat([an, globals]) @ Wg + bg), 2-way k-split
__global__ void k_gupdate(const float* __restrict__ an, const float* __restrict__ g,
                          const float* __restrict__ Wg, const float* __restrict__ bg,
                          float* __restrict__ gout) {
  __shared__ float part[256];
  const int j = threadIdx.x & 127, half = threadIdx.x >> 7;
  float acc = 0.f;
  if (half == 0) {
    for (int k = 0; k < D; ++k) acc = fmaf(an[k], Wg[k * D + j], acc);
  } else {
    for (int k = 0; k < D; ++k) acc = fmaf(g[k], Wg[(D + k) * D + j], acc);
  }
  part[threadIdx.x] = acc;
  __syncthreads();
  if (threadIdx.x < D)
    gout[j] = g[j] + fmaxf(bg[j] + part[j] + part[j + 128], 0.f);
}

extern "C" void kernel_launch(void* const* d_in, const int* in_sizes, int n_in,
                              void* d_out, int out_size, void* d_ws, size_t ws_size,
                              hipStream_t stream) {
  const float* nodes = (const float*)d_in[0];
  const float* globals_ = (const float*)d_in[1];
  const int* senders = (const int*)d_in[2];
  const int* receivers = (const int*)d_in[3];
  const float* W1_w = (const float*)d_in[4];
  const float* W1_b = (const float*)d_in[5];
  const float* W2_w = (const float*)d_in[6];
  const float* W2_b = (const float*)d_in[7];
  const float* W3_w = (const float*)d_in[8];
  const float* W3_b = (const float*)d_in[9];
  const float* Wg_w = (const float*)d_in[10];
  const float* Wg_b = (const float*)d_in[11];
  const int N = in_sizes[0] / D;
  const int E = in_sizes[2];
  const int nbE4 = (E + 1023) / 1024;  // 4 edges/thread
  const int nTile = (N + 31) / 32;

  float* h = (float*)d_out;
  float* gout = h + (size_t)N * D;

  float* ws = (float*)d_ws;
  int* cs = (int*)ws;                        // N   \ zeroed
  int* cr = cs + N;                          // N   |
  float* an = (float*)(cr + N);              // D   |
  int* ovfn = (int*)(an + D);                // 1 (+63 pad, zeroed)
  float* gvec = (float*)(ovfn + 64);         // D
  int* srtp = (int*)(gvec + D);              // N*MAXDEG direct CSR
  int* ovf = srtp + (size_t)N * MAXDEG;      // 2*OVFCAP
  ushort* wt = (ushort*)(ovf + 2 * OVFCAP);  // 128 KB split weights

  (void)hipMemsetAsync(cs, 0, (size_t)(2 * N + D + 64) * sizeof(int), stream);

  hipLaunchKernelGGL(k_front, dim3(nbE4 + 1 + 128), dim3(256), 0, stream,
                     senders, receivers, cs, cr, srtp, ovf, ovfn, E, nbE4,
                     globals_, W3_w, W3_b, gvec, W1_w, W2_w, wt);
  hipLaunchKernelGGL(k_ag2, dim3(nTile), dim3(256), 0, stream,
                     nodes, cr, cs, srtp, ovf, ovfn, wt, W1_b, W2_b, gvec,
                     h, an, N);
  hipLaunchKernelGGL(k_gupdate, dim3(1), dim3(256), 0, stream, an, globals_,
                     Wg_w, Wg_b, gout);
}